// Round 9
// baseline (1886.940 us; speedup 1.0000x reference)
//
#include <hip/hip_runtime.h>
#include <hip/hip_bf16.h>
#include <math.h>

// B=512, T=256, H=512, 4H=2048 gate cols, HALF=256, TGT=28
#define BB   512
#define TT   256
#define HH   512
#define NCOL 2048
#define HALF 256
#define TGT  28

typedef short short8 __attribute__((ext_vector_type(8)));
typedef float f32x4  __attribute__((ext_vector_type(4)));

__device__ __forceinline__ float bf2f(unsigned short u) {
    union { unsigned int i; float f; } v; v.i = ((unsigned int)u) << 16; return v.f;
}
__device__ __forceinline__ unsigned short f2bf(float x) {
    union { float f; unsigned int i; } v; v.f = x;
    unsigned int u = v.i;
    return (unsigned short)((u + 0x7FFFu + ((u >> 16) & 1u)) >> 16);
}
__device__ __forceinline__ float sigmoidf_(float x) {
    return 1.0f / (1.0f + __expf(-x));
}
__device__ __forceinline__ float tanhf_(float x) {
    x = fminf(fmaxf(x, -15.0f), 15.0f);
    float e = __expf(-2.0f * x);
    return (1.0f - e) / (1.0f + e);
}

// Fragment-order address for element (row r, k) of a 16-wide tile:
// plane layout [tile16][kchunk32][ (quad*16 + r15)*8 + k7 ]; tile stride 8192.
__device__ __forceinline__ int frag_addr(int r, int k) {
    return (r >> 4) * 8192 + (k >> 5) * 512 + ((((k >> 3) & 3) << 4) + (r & 15)) * 8 + (k & 7);
}

// prep: W_hh -> hi/lo bf16 planes in B-fragment order (col n = j*4+g);
// zero h plane-buffer 0 and barrier counters; transpose seq -> seqT[t][b].
__global__ __launch_bounds__(256) void prep_kernel(
    const float* __restrict__ Whh, const float* __restrict__ seq,
    unsigned short* __restrict__ Whi, unsigned short* __restrict__ Wlo,
    unsigned short* __restrict__ h0hi, unsigned short* __restrict__ h0lo,
    float* __restrict__ seqT, int* __restrict__ cnt)
{
    int tid = blockIdx.x * 256 + threadIdx.x;   // grid 1024 -> 262144 threads
    h0hi[tid] = 0; h0lo[tid] = 0;
    if (tid < 4096) cnt[tid] = 0;
    if (tid < BB * TT) {
        int b = tid >> 8, t = tid & (TT - 1);
        seqT[t * BB + b] = seq[tid];
    }
    for (int e = tid; e < NCOL * HH; e += 262144) {
        int n = e >> 9;
        int k = e & (HH - 1);
        int j = n >> 2, g = n & 3;
        float w = Whh[(g * HH + j) * HH + k];
        unsigned short hi = f2bf(w);
        float lo = w - bf2f(hi);
        int a = frag_addr(n, k);
        Whi[a] = hi;
        Wlo[a] = f2bf(lo);
    }
}

// Persistent LSTM, all 256 steps. Grid 256 blocks x 512 thr = 1 block/CU
// (LDS 64KB, launch_bounds(512,2) -> VGPR cap 256 -> all blocks resident).
// Block: 32 batch rows x 128 gate cols. Waves: wn in [0,4) x wk in {0,1}.
// W fragments (hi+lo, 32 cols x k-half) PINNED in VGPRs via asm volatile --
// round-8's VGPR_Count=104 proved the compiler was re-loading W inside the
// K-loop every step (W alone needs 128 VGPRs); the volatile asm cannot be
// rematerialized, forcing W register-resident for the whole kernel.
// Per step: stage A (64KB) into LDS via agent-scope 8B atomic loads (IF$
// coherence point), K-loop = ds_read_b128 + MFMA only, partial gates via
// gbuf overlaying the A-buffer.
__global__ __launch_bounds__(512, 2) void lstm_persist(
    const unsigned short* __restrict__ Whi, const unsigned short* __restrict__ Wlo,
    unsigned short* __restrict__ h0hi, unsigned short* __restrict__ h0lo,
    unsigned short* __restrict__ h1hi, unsigned short* __restrict__ h1lo,
    const float* __restrict__ seqT,
    const float* __restrict__ wih,
    const float* __restrict__ bih, const float* __restrict__ bhh,
    int* __restrict__ cnt)
{
    const int bid  = blockIdx.x;
    const int rg   = bid & 15;                   // row-group: rows rg*32..+32
    const int cb   = bid >> 4;                   // col-block: cols cb*128..+128
    const int tid  = threadIdx.x;
    const int lane = tid & 63;
    const int wave = tid >> 6;                   // 0..7
    const int wn   = wave & 3, wk = wave >> 2;   // 4 col-groups x 2 k-halves
    const int col16 = lane & 15, quad = lane >> 4;

    // LDS: A-stage buffer (64KB) overlaid with the gate-partial buffer (32KB).
    __shared__ __align__(16) unsigned char smem[65536];
    short* aS = (short*)smem;                      // [plane2][mt2][8192]
    float (*gS)[32][128] = (float (*)[32][128])smem; // [kh2][row32][col128]

    // ---- load W fragments into registers (once) and PIN them ----
    short8 Wh[2][8], Wl[2][8];
    #pragma unroll
    for (int nt = 0; nt < 2; ++nt) {
        const int tb = (cb * 8 + wn * 2 + nt) * 8192 + lane * 8;
        #pragma unroll
        for (int kc = 0; kc < 8; ++kc) {
            const int a = tb + (wk * 8 + kc) * 512;
            Wh[nt][kc] = *(const short8*)(Whi + a);
            Wl[nt][kc] = *(const short8*)(Wlo + a);
        }
    }
    // volatile asm: not duplicable/rematerializable -> values stay in VGPRs
    #pragma unroll
    for (int nt = 0; nt < 2; ++nt)
        #pragma unroll
        for (int kc = 0; kc < 8; ++kc) {
            asm volatile("" : "+v"(Wh[nt][kc]));
            asm volatile("" : "+v"(Wl[nt][kc]));
        }

    // bias + input weight per accumulator column (loaded once)
    float bn[2], wxn[2];
    #pragma unroll
    for (int nt = 0; nt < 2; ++nt) {
        int n   = cb * 128 + wn * 32 + nt * 16 + col16;
        int src = (n & 3) * HH + (n >> 2);
        bn[nt]  = bih[src] + bhh[src];
        wxn[nt] = wih[src];
    }

    float creg[2] = {0.0f, 0.0f};   // cell state for this thread's 2 j's

    int* mycnt = cnt + rg * TT;

    // epilogue indexing (constant across t): thread -> (row bb, j-pair lj)
    const int bb = tid >> 4;
    const int lj = (tid & 15) * 2;
    const int hbase = frag_addr(rg * 32 + bb, cb * 32 + lj);  // pair contiguous

    for (int t = 0; t < TT; ++t) {
        const unsigned short* hphi = (t & 1) ? h1hi : h0hi;
        const unsigned short* hplo = (t & 1) ? h1lo : h0lo;
        unsigned short* hnhi = (t & 1) ? h0hi : h1hi;
        unsigned short* hnlo = (t & 1) ? h0lo : h1lo;

        // x-loads: t-dependent only -> issue BEFORE the barrier to hide latency
        float xr[2][4];
        if (wk == 0) {
            #pragma unroll
            for (int mt = 0; mt < 2; ++mt)
                #pragma unroll
                for (int r = 0; r < 4; ++r)
                    xr[mt][r] = seqT[t * BB + rg * 32 + mt * 16 + quad * 4 + r];
        }

        if (t > 0 && tid == 0) {
            long spins = 0;
            while (__hip_atomic_load(&mycnt[t - 1], __ATOMIC_RELAXED,
                                     __HIP_MEMORY_SCOPE_AGENT) < 16) {
                __builtin_amdgcn_s_sleep(2);
                if (++spins > 100000000L) break;   // fail loud, never hang
            }
        }
        __syncthreads();   // (1) barrier passed; prior epilogue LDS reads done

        // ---- stage A: 64KB (hi+lo planes, 2 m-tiles) via agent 8B loads ----
        const unsigned short* hp_pl[2] = {hphi, hplo};
        #pragma unroll
        for (int i = 0; i < 16; ++i) {
            int plane = i & 1;
            int flat  = (i >> 1) * 2048 + tid * 4;     // shorts within plane
            int mt    = flat >> 13;
            int inner = flat & 8191;
            const unsigned long long* src = (const unsigned long long*)
                (hp_pl[plane] + (rg * 2 + mt) * 8192 + inner);
            unsigned long long u = __hip_atomic_load(src, __ATOMIC_RELAXED,
                                                     __HIP_MEMORY_SCOPE_AGENT);
            *(unsigned long long*)(aS + plane * 16384 + flat) = u;
        }
        __syncthreads();   // (2) A staged

        // acc init: wk=0 wave carries bias + x*W_ih; wk=1 partial starts at 0
        f32x4 acc[2][2];
        #pragma unroll
        for (int mt = 0; mt < 2; ++mt)
            #pragma unroll
            for (int nt = 0; nt < 2; ++nt)
                #pragma unroll
                for (int r = 0; r < 4; ++r)
                    acc[mt][nt][r] = (wk == 0)
                        ? bn[nt] + xr[mt][r] * wxn[nt] : 0.0f;

        // ---- K-loop: A from LDS (ds_read_b128), W from pinned regs ----
        const int abase = wk * 8 * 512 + lane * 8;
        #pragma unroll
        for (int kc = 0; kc < 8; ++kc) {
            const int o = abase + kc * 512;
            short8 ah0 = *(const short8*)(aS + o);                  // hi, mt0
            short8 ah1 = *(const short8*)(aS + 8192 + o);           // hi, mt1
            short8 al0 = *(const short8*)(aS + 16384 + o);          // lo, mt0
            short8 al1 = *(const short8*)(aS + 16384 + 8192 + o);   // lo, mt1
            acc[0][0] = __builtin_amdgcn_mfma_f32_16x16x32_bf16(ah0, Wh[0][kc], acc[0][0], 0, 0, 0);
            acc[0][1] = __builtin_amdgcn_mfma_f32_16x16x32_bf16(ah0, Wh[1][kc], acc[0][1], 0, 0, 0);
            acc[1][0] = __builtin_amdgcn_mfma_f32_16x16x32_bf16(ah1, Wh[0][kc], acc[1][0], 0, 0, 0);
            acc[1][1] = __builtin_amdgcn_mfma_f32_16x16x32_bf16(ah1, Wh[1][kc], acc[1][1], 0, 0, 0);
            acc[0][0] = __builtin_amdgcn_mfma_f32_16x16x32_bf16(ah0, Wl[0][kc], acc[0][0], 0, 0, 0);
            acc[0][1] = __builtin_amdgcn_mfma_f32_16x16x32_bf16(ah0, Wl[1][kc], acc[0][1], 0, 0, 0);
            acc[1][0] = __builtin_amdgcn_mfma_f32_16x16x32_bf16(ah1, Wl[0][kc], acc[1][0], 0, 0, 0);
            acc[1][1] = __builtin_amdgcn_mfma_f32_16x16x32_bf16(ah1, Wl[1][kc], acc[1][1], 0, 0, 0);
            acc[0][0] = __builtin_amdgcn_mfma_f32_16x16x32_bf16(al0, Wh[0][kc], acc[0][0], 0, 0, 0);
            acc[0][1] = __builtin_amdgcn_mfma_f32_16x16x32_bf16(al0, Wh[1][kc], acc[0][1], 0, 0, 0);
            acc[1][0] = __builtin_amdgcn_mfma_f32_16x16x32_bf16(al1, Wh[0][kc], acc[1][0], 0, 0, 0);
            acc[1][1] = __builtin_amdgcn_mfma_f32_16x16x32_bf16(al1, Wh[1][kc], acc[1][1], 0, 0, 0);
        }
        __syncthreads();   // (3) all A reads done -> safe to overlay gS

        // k-partial gates -> gS overlay
        #pragma unroll
        for (int mt = 0; mt < 2; ++mt)
            #pragma unroll
            for (int nt = 0; nt < 2; ++nt)
                #pragma unroll
                for (int r = 0; r < 4; ++r)
                    gS[wk][mt * 16 + quad * 4 + r][wn * 32 + nt * 16 + col16] = acc[mt][nt][r];
        __syncthreads();   // (4) partials visible

        // gate nonlinearities + c/h update for 2 adjacent j's; paired 4B stores
        {
            f32x4 a0 = *(const f32x4*)(&gS[0][bb][lj * 4]);
            f32x4 b0 = *(const f32x4*)(&gS[1][bb][lj * 4]);
            f32x4 a1 = *(const f32x4*)(&gS[0][bb][(lj + 1) * 4]);
            f32x4 b1 = *(const f32x4*)(&gS[1][bb][(lj + 1) * 4]);
            float h_[2];
            #pragma unroll
            for (int e = 0; e < 2; ++e) {
                f32x4 ga = e ? a1 : a0, gb = e ? b1 : b0;
                float i_ = sigmoidf_(ga[0] + gb[0]);
                float f_ = sigmoidf_(ga[1] + gb[1]);
                float g_ = tanhf_(ga[2] + gb[2]);
                float o_ = sigmoidf_(ga[3] + gb[3]);
                float cn = f_ * creg[e] + i_ * g_;
                creg[e] = cn;
                h_[e] = o_ * tanhf_(cn);
            }
            unsigned short hh0 = f2bf(h_[0]), hh1 = f2bf(h_[1]);
            unsigned int hipk = (unsigned int)hh0 | ((unsigned int)hh1 << 16);
            unsigned int lopk = (unsigned int)f2bf(h_[0] - bf2f(hh0))
                              | ((unsigned int)f2bf(h_[1] - bf2f(hh1)) << 16);
            __hip_atomic_store((unsigned int*)(hnhi + hbase), hipk,
                               __ATOMIC_RELAXED, __HIP_MEMORY_SCOPE_AGENT);
            __hip_atomic_store((unsigned int*)(hnlo + hbase), lopk,
                               __ATOMIC_RELAXED, __HIP_MEMORY_SCOPE_AGENT);
        }

        __syncthreads();   // (5) drains vmcnt: stores ack'd at coherence point
        if (tid == 0)
            atomicAdd(&mycnt[t], 1);
    }
}

// FC tail: hid = relu(h @ fc1_w.T + b); out = hid @ fc2_w.T + b. One block per b.
__global__ __launch_bounds__(256) void fc_kernel(
    const unsigned short* __restrict__ hhi, const unsigned short* __restrict__ hlo,
    const float* __restrict__ fc1w, const float* __restrict__ fc1b,
    const float* __restrict__ fc2w, const float* __restrict__ fc2b,
    float* __restrict__ out)
{
    __shared__ float hS[HH];
    __shared__ float hidS[HALF];
    const int b = blockIdx.x, tid = threadIdx.x;

    for (int k = tid; k < HH; k += 256) {
        int a = frag_addr(b, k);
        hS[k] = bf2f(hhi[a]) + bf2f(hlo[a]);
    }
    __syncthreads();

    float acc = fc1b[tid];
    const float4* wrow = (const float4*)(fc1w + tid * HH);
    #pragma unroll 4
    for (int k4 = 0; k4 < HH / 4; ++k4) {
        float4 w = wrow[k4];
        acc += w.x * hS[k4 * 4] + w.y * hS[k4 * 4 + 1]
             + w.z * hS[k4 * 4 + 2] + w.w * hS[k4 * 4 + 3];
    }
    hidS[tid] = fmaxf(acc, 0.0f);
    __syncthreads();

    if (tid < TGT) {
        float a2 = fc2b[tid];
        const float4* w2 = (const float4*)(fc2w + tid * HALF);
        #pragma unroll 4
        for (int k4 = 0; k4 < HALF / 4; ++k4) {
            float4 w = w2[k4];
            a2 += w.x * hidS[k4 * 4] + w.y * hidS[k4 * 4 + 1]
                + w.z * hidS[k4 * 4 + 2] + w.w * hidS[k4 * 4 + 3];
        }
        out[b * TGT + tid] = a2;
    }
}

extern "C" void kernel_launch(void* const* d_in, const int* in_sizes, int n_in,
                              void* d_out, int out_size, void* d_ws, size_t ws_size,
                              hipStream_t stream)
{
    const float* seq   = (const float*)d_in[0];
    const float* W_ih  = (const float*)d_in[1];
    const float* W_hh  = (const float*)d_in[2];
    const float* b_ih  = (const float*)d_in[3];
    const float* b_hh  = (const float*)d_in[4];
    const float* fc1_w = (const float*)d_in[5];
    const float* fc1_b = (const float*)d_in[6];
    const float* fc2_w = (const float*)d_in[7];
    const float* fc2_b = (const float*)d_in[8];
    float* out = (float*)d_out;

    // ws layout (~6.6 MB total)
    unsigned short* us = (unsigned short*)d_ws;
    unsigned short* Whi  = us;                  // 1,048,576 shorts (2 MB)
    unsigned short* Wlo  = us + 1048576;        // 2 MB
    unsigned short* h0hi = us + 2097152;        // 262,144 shorts each
    unsigned short* h0lo = us + 2359296;
    unsigned short* h1hi = us + 2621440;
    unsigned short* h1lo = us + 2883584;        // shorts end at 3,145,728
    float* seqT = (float*)(us + 3145728);       // 131,072 floats (512 KB)
    int*   cnt  = (int*)(seqT + BB * TT);       // 4,096 ints (16 KB)

    prep_kernel<<<dim3(1024), dim3(256), 0, stream>>>(
        W_hh, seq, Whi, Wlo, h0hi, h0lo, seqT, cnt);

    lstm_persist<<<dim3(256), dim3(512), 0, stream>>>(
        Whi, Wlo, h0hi, h0lo, h1hi, h1lo,
        seqT, W_ih, b_ih, b_hh, cnt);

    // final h (t=255 writes buffer 0)
    fc_kernel<<<dim3(512), dim3(256), 0, stream>>>(
        h0hi, h0lo, fc1_w, fc1_b, fc2_w, fc2_b, out);
}

// Round 10
// 1188.088 us; speedup vs baseline: 1.5882x; 1.5882x over previous
//
#include <hip/hip_runtime.h>
#include <hip/hip_bf16.h>
#include <math.h>

// B=512, T=256, H=512, 4H=2048 gate cols, HALF=256, TGT=28
#define BB   512
#define TT   256
#define HH   512
#define NCOL 2048
#define HALF 256
#define TGT  28

typedef short short8 __attribute__((ext_vector_type(8)));
typedef float f32x4  __attribute__((ext_vector_type(4)));

__device__ __forceinline__ float bf2f(unsigned short u) {
    union { unsigned int i; float f; } v; v.i = ((unsigned int)u) << 16; return v.f;
}
__device__ __forceinline__ unsigned short f2bf(float x) {
    union { float f; unsigned int i; } v; v.f = x;
    unsigned int u = v.i;
    return (unsigned short)((u + 0x7FFFu + ((u >> 16) & 1u)) >> 16);
}
__device__ __forceinline__ float sigmoidf_(float x) {
    return 1.0f / (1.0f + __expf(-x));
}
__device__ __forceinline__ float tanhf_(float x) {
    x = fminf(fmaxf(x, -15.0f), 15.0f);
    float e = __expf(-2.0f * x);
    return (1.0f - e) / (1.0f + e);
}

// Fragment-order address for element (row r, k) of a 16-wide tile:
// plane layout [tile16][kchunk32][ (quad*16 + r15)*8 + k7 ]; tile stride 8192.
__device__ __forceinline__ int frag_addr(int r, int k) {
    return (r >> 4) * 8192 + (k >> 5) * 512 + ((((k >> 3) & 3) << 4) + (r & 15)) * 8 + (k & 7);
}

// async global->LDS 16B/lane DMA with device-coherent policy (sc0|sc1=0x11):
// misses L1 and L2, reads the IF$ coherence point -- same freshness semantics
// as the agent-scope atomic loads it replaces, but no VGPR round-trip and no
// LDS-write instructions. LDS dest is wave-uniform base + lane*16 [m104].
__device__ __forceinline__ void async_ld16(
    const unsigned short* gp, unsigned short* lp_base)
{
    __builtin_amdgcn_global_load_lds(
        (const __attribute__((address_space(1))) unsigned int*)gp,
        (__attribute__((address_space(3))) unsigned int*)lp_base,
        16, 0, 0x11);
}

// prep: W_hh -> hi/lo bf16 planes in B-fragment order (col n = j*4+g);
// zero h plane-buffer 0 and barrier counters; transpose seq -> seqT[t][b].
__global__ __launch_bounds__(256) void prep_kernel(
    const float* __restrict__ Whh, const float* __restrict__ seq,
    unsigned short* __restrict__ Whi, unsigned short* __restrict__ Wlo,
    unsigned short* __restrict__ h0hi, unsigned short* __restrict__ h0lo,
    float* __restrict__ seqT, int* __restrict__ cnt)
{
    int tid = blockIdx.x * 256 + threadIdx.x;   // grid 1024 -> 262144 threads
    h0hi[tid] = 0; h0lo[tid] = 0;
    if (tid < 4096) cnt[tid] = 0;
    if (tid < BB * TT) {
        int b = tid >> 8, t = tid & (TT - 1);
        seqT[t * BB + b] = seq[tid];
    }
    for (int e = tid; e < NCOL * HH; e += 262144) {
        int n = e >> 9;
        int k = e & (HH - 1);
        int j = n >> 2, g = n & 3;
        float w = Whh[(g * HH + j) * HH + k];
        unsigned short hi = f2bf(w);
        float lo = w - bf2f(hi);
        int a = frag_addr(n, k);
        Whi[a] = hi;
        Wlo[a] = f2bf(lo);
    }
}

// Persistent LSTM, all 256 steps. Grid 256 blocks x 512 thr = 1 block/CU
// (LDS 96KB -> 1 block/CU; launch_bounds(512,2) -> VGPR cap 256; all 256
// blocks resident by construction).
// Block: 32 batch rows x 128 gate cols. Waves: wn in [0,4) x wk in {0,1}.
// W fragments live in the unified VGPR/AGPR file (compiler keeps them
// AGPR-resident; round-9 pin test confirmed residency).
// Per step (4 barriers): poll -> S1 -> async DMA stage (64KB) -> S2 ->
// K-loop (ds_read_b128 + MFMA) -> gS write (separate 32KB region, no WAR
// barrier needed) -> S3 -> epilogue + h store (agent, write-through) -> S4
// -> counter bump.
__global__ __launch_bounds__(512, 2) void lstm_persist(
    const unsigned short* __restrict__ Whi, const unsigned short* __restrict__ Wlo,
    unsigned short* __restrict__ h0hi, unsigned short* __restrict__ h0lo,
    unsigned short* __restrict__ h1hi, unsigned short* __restrict__ h1lo,
    const float* __restrict__ seqT,
    const float* __restrict__ wih,
    const float* __restrict__ bih, const float* __restrict__ bhh,
    int* __restrict__ cnt)
{
    const int bid  = blockIdx.x;
    const int rg   = bid & 15;                   // row-group: rows rg*32..+32
    const int cb   = bid >> 4;                   // col-block: cols cb*128..+128
    const int tid  = threadIdx.x;
    const int lane = tid & 63;
    const int wave = tid >> 6;                   // 0..7
    const int wn   = wave & 3, wk = wave >> 2;   // 4 col-groups x 2 k-halves
    const int col16 = lane & 15, quad = lane >> 4;

    // LDS: A-stage buffer (64KB) + separate gate-partial buffer (32KB).
    __shared__ __align__(16) short aS[32768];          // [plane2][mt2][8192]
    __shared__ __align__(16) float gS[2][32][128];     // [kh2][row32][col128]

    // ---- load W fragments into registers (once) ----
    short8 Wh[2][8], Wl[2][8];
    #pragma unroll
    for (int nt = 0; nt < 2; ++nt) {
        const int tb = (cb * 8 + wn * 2 + nt) * 8192 + lane * 8;
        #pragma unroll
        for (int kc = 0; kc < 8; ++kc) {
            const int a = tb + (wk * 8 + kc) * 512;
            Wh[nt][kc] = *(const short8*)(Whi + a);
            Wl[nt][kc] = *(const short8*)(Wlo + a);
        }
    }
    #pragma unroll
    for (int nt = 0; nt < 2; ++nt)
        #pragma unroll
        for (int kc = 0; kc < 8; ++kc) {
            asm volatile("" : "+v"(Wh[nt][kc]));
            asm volatile("" : "+v"(Wl[nt][kc]));
        }

    // bias + input weight per accumulator column (loaded once)
    float bn[2], wxn[2];
    #pragma unroll
    for (int nt = 0; nt < 2; ++nt) {
        int n   = cb * 128 + wn * 32 + nt * 16 + col16;
        int src = (n & 3) * HH + (n >> 2);
        bn[nt]  = bih[src] + bhh[src];
        wxn[nt] = wih[src];
    }

    float creg[2] = {0.0f, 0.0f};   // cell state for this thread's 2 j's

    int* mycnt = cnt + rg * TT;

    // epilogue indexing (constant across t): thread -> (row bb, j-pair lj)
    const int bb = tid >> 4;
    const int lj = (tid & 15) * 2;
    const int hbase = frag_addr(rg * 32 + bb, cb * 32 + lj);  // pair contiguous

    for (int t = 0; t < TT; ++t) {
        const unsigned short* hphi = (t & 1) ? h1hi : h0hi;
        const unsigned short* hplo = (t & 1) ? h1lo : h0lo;
        unsigned short* hnhi = (t & 1) ? h0hi : h1hi;
        unsigned short* hnlo = (t & 1) ? h0lo : h1lo;
        const unsigned short* hp_pl[2] = {hphi, hplo};

        // x-loads: t-dependent only -> issue BEFORE the barrier to hide latency
        float xr[2][4];
        if (wk == 0) {
            #pragma unroll
            for (int mt = 0; mt < 2; ++mt)
                #pragma unroll
                for (int r = 0; r < 4; ++r)
                    xr[mt][r] = seqT[t * BB + rg * 32 + mt * 16 + quad * 4 + r];
        }

        if (t > 0 && tid == 0) {
            long spins = 0;
            while (__hip_atomic_load(&mycnt[t - 1], __ATOMIC_RELAXED,
                                     __HIP_MEMORY_SCOPE_AGENT) < 16) {
                __builtin_amdgcn_s_sleep(1);
                if (++spins > 100000000L) break;   // fail loud, never hang
            }
        }
        __syncthreads();   // S1: barrier passed

        // ---- stage A: 64KB via async DMA (8 x 1KB wave-instrs per wave) ----
        // wave-instr j covers LDS shorts [ (j>=32)*16384 + (j&31)*512 , +512 )
        #pragma unroll
        for (int i = 0; i < 8; ++i) {
            const int j     = wave * 8 + i;
            const int plane = j >> 5;
            const int s     = (j & 31) * 512 + lane * 8;  // short idx in plane
            const int mt    = s >> 13;
            const unsigned short* gp =
                hp_pl[plane] + (rg * 2 + mt) * 8192 + (s & 8191);
            unsigned short* lp = (unsigned short*)aS + plane * 16384 + (j & 31) * 512;
            async_ld16(gp, lp);
        }
        __syncthreads();   // S2: drains vmcnt -> A staged

        // acc init: wk=0 wave carries bias + x*W_ih; wk=1 partial starts at 0
        f32x4 acc[2][2];
        #pragma unroll
        for (int mt = 0; mt < 2; ++mt)
            #pragma unroll
            for (int nt = 0; nt < 2; ++nt)
                #pragma unroll
                for (int r = 0; r < 4; ++r)
                    acc[mt][nt][r] = (wk == 0)
                        ? bn[nt] + xr[mt][r] * wxn[nt] : 0.0f;

        // ---- K-loop: A from LDS (ds_read_b128), W from regs ----
        const int abase = wk * 8 * 512 + lane * 8;
        #pragma unroll
        for (int kc = 0; kc < 8; ++kc) {
            const int o = abase + kc * 512;
            short8 ah0 = *(const short8*)((unsigned short*)aS + o);
            short8 ah1 = *(const short8*)((unsigned short*)aS + 8192 + o);
            short8 al0 = *(const short8*)((unsigned short*)aS + 16384 + o);
            short8 al1 = *(const short8*)((unsigned short*)aS + 16384 + 8192 + o);
            acc[0][0] = __builtin_amdgcn_mfma_f32_16x16x32_bf16(ah0, Wh[0][kc], acc[0][0], 0, 0, 0);
            acc[0][1] = __builtin_amdgcn_mfma_f32_16x16x32_bf16(ah0, Wh[1][kc], acc[0][1], 0, 0, 0);
            acc[1][0] = __builtin_amdgcn_mfma_f32_16x16x32_bf16(ah1, Wh[0][kc], acc[1][0], 0, 0, 0);
            acc[1][1] = __builtin_amdgcn_mfma_f32_16x16x32_bf16(ah1, Wh[1][kc], acc[1][1], 0, 0, 0);
            acc[0][0] = __builtin_amdgcn_mfma_f32_16x16x32_bf16(ah0, Wl[0][kc], acc[0][0], 0, 0, 0);
            acc[0][1] = __builtin_amdgcn_mfma_f32_16x16x32_bf16(ah0, Wl[1][kc], acc[0][1], 0, 0, 0);
            acc[1][0] = __builtin_amdgcn_mfma_f32_16x16x32_bf16(ah1, Wl[0][kc], acc[1][0], 0, 0, 0);
            acc[1][1] = __builtin_amdgcn_mfma_f32_16x16x32_bf16(ah1, Wl[1][kc], acc[1][1], 0, 0, 0);
            acc[0][0] = __builtin_amdgcn_mfma_f32_16x16x32_bf16(al0, Wh[0][kc], acc[0][0], 0, 0, 0);
            acc[0][1] = __builtin_amdgcn_mfma_f32_16x16x32_bf16(al0, Wh[1][kc], acc[0][1], 0, 0, 0);
            acc[1][0] = __builtin_amdgcn_mfma_f32_16x16x32_bf16(al1, Wh[0][kc], acc[1][0], 0, 0, 0);
            acc[1][1] = __builtin_amdgcn_mfma_f32_16x16x32_bf16(al1, Wh[1][kc], acc[1][1], 0, 0, 0);
        }

        // k-partial gates -> gS (separate region: no WAR vs aS, no barrier)
        #pragma unroll
        for (int mt = 0; mt < 2; ++mt)
            #pragma unroll
            for (int nt = 0; nt < 2; ++nt)
                #pragma unroll
                for (int r = 0; r < 4; ++r)
                    gS[wk][mt * 16 + quad * 4 + r][wn * 32 + nt * 16 + col16] = acc[mt][nt][r];
        __syncthreads();   // S3: partials visible

        // gate nonlinearities + c/h update for 2 adjacent j's; paired 4B stores
        {
            f32x4 a0 = *(const f32x4*)(&gS[0][bb][lj * 4]);
            f32x4 b0 = *(const f32x4*)(&gS[1][bb][lj * 4]);
            f32x4 a1 = *(const f32x4*)(&gS[0][bb][(lj + 1) * 4]);
            f32x4 b1 = *(const f32x4*)(&gS[1][bb][(lj + 1) * 4]);
            float h_[2];
            #pragma unroll
            for (int e = 0; e < 2; ++e) {
                f32x4 ga = e ? a1 : a0, gb = e ? b1 : b0;
                float i_ = sigmoidf_(ga[0] + gb[0]);
                float f_ = sigmoidf_(ga[1] + gb[1]);
                float g_ = tanhf_(ga[2] + gb[2]);
                float o_ = sigmoidf_(ga[3] + gb[3]);
                float cn = f_ * creg[e] + i_ * g_;
                creg[e] = cn;
                h_[e] = o_ * tanhf_(cn);
            }
            unsigned short hh0 = f2bf(h_[0]), hh1 = f2bf(h_[1]);
            unsigned int hipk = (unsigned int)hh0 | ((unsigned int)hh1 << 16);
            unsigned int lopk = (unsigned int)f2bf(h_[0] - bf2f(hh0))
                              | ((unsigned int)f2bf(h_[1] - bf2f(hh1)) << 16);
            __hip_atomic_store((unsigned int*)(hnhi + hbase), hipk,
                               __ATOMIC_RELAXED, __HIP_MEMORY_SCOPE_AGENT);
            __hip_atomic_store((unsigned int*)(hnlo + hbase), lopk,
                               __ATOMIC_RELAXED, __HIP_MEMORY_SCOPE_AGENT);
        }

        __syncthreads();   // S4: drains vmcnt -> stores ack'd at coherence point
        if (tid == 0)
            atomicAdd(&mycnt[t], 1);
    }
}

// FC tail: hid = relu(h @ fc1_w.T + b); out = hid @ fc2_w.T + b. One block per b.
__global__ __launch_bounds__(256) void fc_kernel(
    const unsigned short* __restrict__ hhi, const unsigned short* __restrict__ hlo,
    const float* __restrict__ fc1w, const float* __restrict__ fc1b,
    const float* __restrict__ fc2w, const float* __restrict__ fc2b,
    float* __restrict__ out)
{
    __shared__ float hS[HH];
    __shared__ float hidS[HALF];
    const int b = blockIdx.x, tid = threadIdx.x;

    for (int k = tid; k < HH; k += 256) {
        int a = frag_addr(b, k);
        hS[k] = bf2f(hhi[a]) + bf2f(hlo[a]);
    }
    __syncthreads();

    float acc = fc1b[tid];
    const float4* wrow = (const float4*)(fc1w + tid * HH);
    #pragma unroll 4
    for (int k4 = 0; k4 < HH / 4; ++k4) {
        float4 w = wrow[k4];
        acc += w.x * hS[k4 * 4] + w.y * hS[k4 * 4 + 1]
             + w.z * hS[k4 * 4 + 2] + w.w * hS[k4 * 4 + 3];
    }
    hidS[tid] = fmaxf(acc, 0.0f);
    __syncthreads();

    if (tid < TGT) {
        float a2 = fc2b[tid];
        const float4* w2 = (const float4*)(fc2w + tid * HALF);
        #pragma unroll 4
        for (int k4 = 0; k4 < HALF / 4; ++k4) {
            float4 w = w2[k4];
            a2 += w.x * hidS[k4 * 4] + w.y * hidS[k4 * 4 + 1]
                + w.z * hidS[k4 * 4 + 2] + w.w * hidS[k4 * 4 + 3];
        }
        out[b * TGT + tid] = a2;
    }
}

extern "C" void kernel_launch(void* const* d_in, const int* in_sizes, int n_in,
                              void* d_out, int out_size, void* d_ws, size_t ws_size,
                              hipStream_t stream)
{
    const float* seq   = (const float*)d_in[0];
    const float* W_ih  = (const float*)d_in[1];
    const float* W_hh  = (const float*)d_in[2];
    const float* b_ih  = (const float*)d_in[3];
    const float* b_hh  = (const float*)d_in[4];
    const float* fc1_w = (const float*)d_in[5];
    const float* fc1_b = (const float*)d_in[6];
    const float* fc2_w = (const float*)d_in[7];
    const float* fc2_b = (const float*)d_in[8];
    float* out = (float*)d_out;

    // ws layout (~6.6 MB total)
    unsigned short* us = (unsigned short*)d_ws;
    unsigned short* Whi  = us;                  // 1,048,576 shorts (2 MB)
    unsigned short* Wlo  = us + 1048576;        // 2 MB
    unsigned short* h0hi = us + 2097152;        // 262,144 shorts each
    unsigned short* h0lo = us + 2359296;
    unsigned short* h1hi = us + 2621440;
    unsigned short* h1lo = us + 2883584;        // shorts end at 3,145,728
    float* seqT = (float*)(us + 3145728);       // 131,072 floats (512 KB)
    int*   cnt  = (int*)(seqT + BB * TT);       // 4,096 ints (16 KB)

    prep_kernel<<<dim3(1024), dim3(256), 0, stream>>>(
        W_hh, seq, Whi, Wlo, h0hi, h0lo, seqT, cnt);

    lstm_persist<<<dim3(256), dim3(512), 0, stream>>>(
        Whi, Wlo, h0hi, h0lo, h1hi, h1lo,
        seqT, W_ih, b_ih, b_hh, cnt);

    // final h (t=255 writes buffer 0)
    fc_kernel<<<dim3(512), dim3(256), 0, stream>>>(
        h0hi, h0lo, fc1_w, fc1_b, fc2_w, fc2_b, out);
}